// Round 10
// baseline (97.459 us; speedup 1.0000x reference)
//
#include <hip/hip_runtime.h>

typedef float floatx2 __attribute__((ext_vector_type(2)));

// Problem constants (fixed by setup_inputs): B=16, C=3, H=W=768.
constexpr int B = 16, C = 3, H = 768, W = 768;
constexpr int HW = H * W;
constexpr float EPS2 = 1e-6f;         // 0.001^2
constexpr float MASK_THRESH = 0.9999f;
constexpr int NXCD = 8;

// Tiling: 64x64 px per block, margin 16 covers |flow|<=16 (4 sigma of N(0,16)).
// Window overfetch (96x96)/(64x64) = 2.25x (was 3x at 32x64 tiles).
constexpr int TH = 64, TW = 64, M = 16;
constexpr int WINR = TH + 2 * M;      // 96
constexpr int WINC = TW + 2 * M;      // 96 payload columns
constexpr int WSTRIDE = 101;          // row stride in words; 101%32=5, coprime
constexpr int TILES_H = H / TH;       // 12
constexpr int TILES_W = W / TW;       // 12
constexpr int NTILES = B * TILES_H * TILES_W;  // 2304
constexpr int NIT = 8;                // 8 iterations x 2 px/thread = 16 px

__global__ __launch_bounds__(256, 4) void warp_charb_fp8_kernel(
    const float* __restrict__ img1,
    const float* __restrict__ img2,
    const float* __restrict__ uv,
    float* __restrict__ partial)
{
    // XCD-chunked swizzle: contiguous band of tiles per XCD (2304 % 8 == 0).
    const int bid = blockIdx.x;
    const int tile = (bid % NXCD) * (NTILES / NXCD) + bid / NXCD;
    const int b  = tile / (TILES_H * TILES_W);
    const int tr = tile - b * (TILES_H * TILES_W);
    const int th = tr / TILES_W;
    const int tw = tr - th * TILES_W;
    const int h0 = th * TH;
    const int w0 = tw * TW;
    const int base_r = h0 - M;
    const int base_c = w0 - M;
    const int t = threadIdx.x;
    const int lane = t & 63;
    const int wrow = t >> 6;               // 0..3
    const int rgrp = lane >> 5;            // 0/1: which row of the pair
    const int cp   = lane & 31;            // col-pair index
    const int colbase = w0 + 2 * cp;

    // Packed RGBA-fp8 window: one u32 per pixel holds all 3 channels.
    // 96*101*4 = 38784 B -> 4 blocks/CU LDS cap.
    __shared__ unsigned win[WINR][WSTRIDE];

    const float* __restrict__ i1b = img1 + b * (C * HW);
    const float* __restrict__ uvb = uv + b * (2 * HW);
    const float* __restrict__ i2b = img2 + b * (C * HW);

    // ---- Stage gather window (coalesced float4 x3 -> packed fp8) ----------
    // base_c and gc are multiples of 4, W%4==0 => every 4-chunk is either
    // fully in-bounds or fully OOB; no partial case.
    // unroll 1 is load-bearing: full unroll hoists 27 float4 loads ->
    // VGPR spill to scratch (rounds 8/9: WRITE_SIZE 64.6 MB of scratch
    // round-trips). One pass = 3 float4 in flight; TLP covers latency.
    constexpr int CH4 = WINC / 4;             // 24
#pragma unroll 1
    for (int s = 0; s < (WINR * CH4) / 256; ++s) {   // 9 passes
        const int idx = t + s * 256;
        const int wy = idx / CH4;
        const int j4 = idx - wy * CH4;
        const int gr = base_r + wy;
        const int gc = base_c + 4 * j4;
        unsigned pk0 = 0u, pk1 = 0u, pk2 = 0u, pk3 = 0u;
        if ((unsigned)gr < (unsigned)H && (unsigned)gc <= (unsigned)(W - 4)) {
            const float* __restrict__ rp = i1b + gr * W + gc;
            const float4 r4 = *(const float4*)(rp);
            const float4 g4 = *(const float4*)(rp + HW);
            const float4 b4 = *(const float4*)(rp + 2 * HW);
            int v;
            v = __builtin_amdgcn_cvt_pk_fp8_f32(r4.x, g4.x, 0, false);
            pk0 = (unsigned)__builtin_amdgcn_cvt_pk_fp8_f32(b4.x, 0.0f, v, true);
            v = __builtin_amdgcn_cvt_pk_fp8_f32(r4.y, g4.y, 0, false);
            pk1 = (unsigned)__builtin_amdgcn_cvt_pk_fp8_f32(b4.y, 0.0f, v, true);
            v = __builtin_amdgcn_cvt_pk_fp8_f32(r4.z, g4.z, 0, false);
            pk2 = (unsigned)__builtin_amdgcn_cvt_pk_fp8_f32(b4.z, 0.0f, v, true);
            v = __builtin_amdgcn_cvt_pk_fp8_f32(r4.w, g4.w, 0, false);
            pk3 = (unsigned)__builtin_amdgcn_cvt_pk_fp8_f32(b4.w, 0.0f, v, true);
        }
        unsigned* __restrict__ dst = &win[wy][4 * j4];
        dst[0] = pk0; dst[1] = pk1; dst[2] = pk2; dst[3] = pk3;
    }
    __syncthreads();

    // ---- Warp + Charbonnier: 8 iters x 2 independent pixels ---------------
    auto px_charb = [&](int w, int h, float u, float v,
                        float r2, float g2, float b2) -> float {
        const float px = (float)w + u;
        const float py = (float)h + v;
        const float fx0 = floorf(px);
        const float fy0 = floorf(py);
        const float wx1 = px - fx0, wx0 = 1.0f - wx1;
        const float wy1 = py - fy0, wy0 = 1.0f - wy1;
        const int ix0 = (int)fx0, iy0 = (int)fy0;
        const int ix1 = ix0 + 1, iy1 = iy0 + 1;
        const float bx0 = ((unsigned)ix0 < (unsigned)W) ? 1.0f : 0.0f;
        const float bx1 = ((unsigned)ix1 < (unsigned)W) ? 1.0f : 0.0f;
        const float by0 = ((unsigned)iy0 < (unsigned)H) ? 1.0f : 0.0f;
        const float by1 = ((unsigned)iy1 < (unsigned)H) ? 1.0f : 0.0f;
        // zeros-padding: OOB corner weights are 0 (same arithmetic as ref)
        float w00 = wx0 * wy0 * (bx0 * by0);
        float w10 = wx1 * wy0 * (bx1 * by0);
        float w01 = wx0 * wy1 * (bx0 * by1);
        float w11 = wx1 * wy1 * (bx1 * by1);
        const float m = w00 + w10 + w01 + w11;      // grid_sample(ones)
        const float mbit = (m < MASK_THRESH) ? 0.0f : 1.0f;
        w00 *= mbit; w10 *= mbit; w01 *= mbit; w11 *= mbit;
        const int x0c = min(max(ix0, 0), W - 1);
        const int x1c = min(max(ix1, 0), W - 1);
        const int y0c = min(max(iy0, 0), H - 1);
        const int y1c = min(max(iy1, 0), H - 1);

        float vr, vg, vb_;
        const bool inwin = (x0c >= base_c) & (x1c < base_c + WINC) &
                           (y0c >= base_r) & (y1c < base_r + WINR);
        if (inwin) {
            const int lx0 = x0c - base_c, lx1 = x1c - base_c;
            const int ly0 = y0c - base_r, ly1 = y1c - base_r;
            const int c00 = (int)win[ly0][lx0];
            const int c10 = (int)win[ly0][lx1];
            const int c01 = (int)win[ly1][lx0];
            const int c11 = (int)win[ly1][lx1];
            const floatx2 rg00 = __builtin_amdgcn_cvt_pk_f32_fp8(c00, false);
            const floatx2 rg10 = __builtin_amdgcn_cvt_pk_f32_fp8(c10, false);
            const floatx2 rg01 = __builtin_amdgcn_cvt_pk_f32_fp8(c01, false);
            const floatx2 rg11 = __builtin_amdgcn_cvt_pk_f32_fp8(c11, false);
            const float b00 = __builtin_amdgcn_cvt_f32_fp8(c00, 2);
            const float b10 = __builtin_amdgcn_cvt_f32_fp8(c10, 2);
            const float b01 = __builtin_amdgcn_cvt_f32_fp8(c01, 2);
            const float b11 = __builtin_amdgcn_cvt_f32_fp8(c11, 2);
            vr  = w00 * rg00.x + w10 * rg10.x + w01 * rg01.x + w11 * rg11.x;
            vg  = w00 * rg00.y + w10 * rg10.y + w01 * rg01.y + w11 * rg11.y;
            vb_ = w00 * b00   + w10 * b10   + w01 * b01   + w11 * b11;
        } else {
            const int o00 = y0c * W + x0c;
            const int o10 = y0c * W + x1c;
            const int o01 = y1c * W + x0c;
            const int o11 = y1c * W + x1c;
            const float* __restrict__ p0 = i1b;
            const float* __restrict__ p1 = i1b + HW;
            const float* __restrict__ p2 = i1b + 2 * HW;
            vr  = w00 * p0[o00] + w10 * p0[o10] + w01 * p0[o01] + w11 * p0[o11];
            vg  = w00 * p1[o00] + w10 * p1[o10] + w01 * p1[o01] + w11 * p1[o11];
            vb_ = w00 * p2[o00] + w10 * p2[o10] + w01 * p2[o01] + w11 * p2[o11];
        }
        const float dr = vr  - r2;
        const float dg = vg  - g2;
        const float db = vb_ - b2;
        // v_sqrt_f32 direct (~1 ulp) instead of sqrtf's ~8-instr fixup chain
        return __builtin_amdgcn_sqrtf(fmaf(dr, dr, EPS2))
             + __builtin_amdgcn_sqrtf(fmaf(dg, dg, EPS2))
             + __builtin_amdgcn_sqrtf(fmaf(db, db, EPS2));
    };

    float acc = 0.0f;
#pragma unroll
    for (int it = 0; it < NIT; ++it) {
        const int h = h0 + 8 * it + 2 * wrow + rgrp;
        const int off = h * W + colbase;
        const float2 uu = *(const float2*)(uvb + off);
        const float2 vv = *(const float2*)(uvb + HW + off);
        const float2 r2 = *(const float2*)(i2b + off);
        const float2 g2 = *(const float2*)(i2b + HW + off);
        const float2 b2 = *(const float2*)(i2b + 2 * HW + off);
        acc += px_charb(colbase,     h, uu.x, vv.x, r2.x, g2.x, b2.x);
        acc += px_charb(colbase + 1, h, uu.y, vv.y, r2.y, g2.y, b2.y);
    }

    // block reduction: 4 waves of 64
#pragma unroll
    for (int offr = 32; offr > 0; offr >>= 1)
        acc += __shfl_down(acc, offr, 64);
    __shared__ float smem[4];
    if ((t & 63) == 0) smem[t >> 6] = acc;
    __syncthreads();
    if (t == 0)
        partial[blockIdx.x] = (smem[0] + smem[1]) + (smem[2] + smem[3]);
}

// Reduce 2304 partials -> scalar mean. Single block, float4 loads.
__global__ __launch_bounds__(256) void reduce_partial_kernel(
    const float* __restrict__ partial, float* __restrict__ out)
{
    float acc = 0.0f;
    const float4* __restrict__ p4 = (const float4*)partial;  // 576 float4
    for (int i = threadIdx.x; i < NTILES / 4; i += 256) {
        const float4 v = p4[i];
        acc += (v.x + v.y) + (v.z + v.w);
    }
#pragma unroll
    for (int off = 32; off > 0; off >>= 1)
        acc += __shfl_down(acc, off, 64);
    __shared__ float smem[4];
    if ((threadIdx.x & 63) == 0) smem[threadIdx.x >> 6] = acc;
    __syncthreads();
    if (threadIdx.x == 0) {
        const float s = (smem[0] + smem[1]) + (smem[2] + smem[3]);
        out[0] = s * (1.0f / (float)((long long)B * C * H * W));
    }
}

extern "C" void kernel_launch(void* const* d_in, const int* in_sizes, int n_in,
                              void* d_out, int out_size, void* d_ws, size_t ws_size,
                              hipStream_t stream) {
    const float* img1 = (const float*)d_in[0];
    const float* img2 = (const float*)d_in[1];
    const float* uv   = (const float*)d_in[2];
    float* out = (float*)d_out;
    float* partial = (float*)d_ws;   // NTILES floats = 9.2 KiB

    warp_charb_fp8_kernel<<<NTILES, 256, 0, stream>>>(img1, img2, uv, partial);
    reduce_partial_kernel<<<1, 256, 0, stream>>>(partial, out);
}

// Round 11
// 67.429 us; speedup vs baseline: 1.4454x; 1.4454x over previous
//
#include <hip/hip_runtime.h>

typedef float floatx2 __attribute__((ext_vector_type(2)));

// Problem constants (fixed by setup_inputs): B=16, C=3, H=W=768.
constexpr int B = 16, C = 3, H = 768, W = 768;
constexpr int HW = H * W;
constexpr float EPS2 = 1e-6f;         // 0.001^2
constexpr float MASK_THRESH = 0.9999f;
constexpr int NXCD = 8;

// Tiling: 64x64 px per block, margin 16 covers |flow|<=16 (4 sigma of N(0,16)).
// Window overfetch (96x96)/(64x64) = 2.25x (was 3x at 32x64 tiles).
constexpr int TH = 64, TW = 64, M = 16;
constexpr int WINR = TH + 2 * M;      // 96
constexpr int WINC = TW + 2 * M;      // 96 payload columns
constexpr int WSTRIDE = 101;          // row stride in words; 101%32=5, coprime
constexpr int TILES_H = H / TH;       // 12
constexpr int TILES_W = W / TW;       // 12
constexpr int NTILES = B * TILES_H * TILES_W;  // 2304
constexpr int NIT = 8;                // 8 iterations x 2 px/thread = 16 px

__global__ __launch_bounds__(256, 4) void warp_charb_fp8_kernel(
    const float* __restrict__ img1,
    const float* __restrict__ img2,
    const float* __restrict__ uv,
    float* __restrict__ partial)
{
    // XCD-chunked swizzle: contiguous band of tiles per XCD (2304 % 8 == 0).
    const int bid = blockIdx.x;
    const int tile = (bid % NXCD) * (NTILES / NXCD) + bid / NXCD;
    const int b  = tile / (TILES_H * TILES_W);
    const int tr = tile - b * (TILES_H * TILES_W);
    const int th = tr / TILES_W;
    const int tw = tr - th * TILES_W;
    const int h0 = th * TH;
    const int w0 = tw * TW;
    const int base_r = h0 - M;
    const int base_c = w0 - M;
    const int t = threadIdx.x;
    const int lane = t & 63;
    const int wrow = t >> 6;               // 0..3
    const int rgrp = lane >> 5;            // 0/1: which row of the pair
    const int cp   = lane & 31;            // col-pair index
    const int colbase = w0 + 2 * cp;

    // Packed RGBA-fp8 window: one u32 per pixel holds all 3 channels.
    // 96*101*4 = 38784 B -> 4 blocks/CU LDS cap.
    __shared__ unsigned win[WINR][WSTRIDE];

    const float* __restrict__ i1b = img1 + b * (C * HW);
    const float* __restrict__ uvb = uv + b * (2 * HW);
    const float* __restrict__ i2b = img2 + b * (C * HW);

    // ---- Stage gather window (coalesced float4 x3 -> packed fp8) ----------
    // base_c and gc are multiples of 4, W%4==0 => every 4-chunk is either
    // fully in-bounds or fully OOB; no partial case.
    constexpr int CH4 = WINC / 4;             // 24
#pragma unroll 1
    for (int s = 0; s < (WINR * CH4) / 256; ++s) {   // 9 passes
        const int idx = t + s * 256;
        const int wy = idx / CH4;
        const int j4 = idx - wy * CH4;
        const int gr = base_r + wy;
        const int gc = base_c + 4 * j4;
        unsigned pk0 = 0u, pk1 = 0u, pk2 = 0u, pk3 = 0u;
        if ((unsigned)gr < (unsigned)H && (unsigned)gc <= (unsigned)(W - 4)) {
            const float* __restrict__ rp = i1b + gr * W + gc;
            const float4 r4 = *(const float4*)(rp);
            const float4 g4 = *(const float4*)(rp + HW);
            const float4 b4 = *(const float4*)(rp + 2 * HW);
            int v;
            v = __builtin_amdgcn_cvt_pk_fp8_f32(r4.x, g4.x, 0, false);
            pk0 = (unsigned)__builtin_amdgcn_cvt_pk_fp8_f32(b4.x, 0.0f, v, true);
            v = __builtin_amdgcn_cvt_pk_fp8_f32(r4.y, g4.y, 0, false);
            pk1 = (unsigned)__builtin_amdgcn_cvt_pk_fp8_f32(b4.y, 0.0f, v, true);
            v = __builtin_amdgcn_cvt_pk_fp8_f32(r4.z, g4.z, 0, false);
            pk2 = (unsigned)__builtin_amdgcn_cvt_pk_fp8_f32(b4.z, 0.0f, v, true);
            v = __builtin_amdgcn_cvt_pk_fp8_f32(r4.w, g4.w, 0, false);
            pk3 = (unsigned)__builtin_amdgcn_cvt_pk_fp8_f32(b4.w, 0.0f, v, true);
        }
        unsigned* __restrict__ dst = &win[wy][4 * j4];
        dst[0] = pk0; dst[1] = pk1; dst[2] = pk2; dst[3] = pk3;
    }
    __syncthreads();

    // ---- Warp + Charbonnier: 8 iters x 2 independent pixels ---------------
    auto px_charb = [&](int w, int h, float u, float v,
                        float r2, float g2, float b2) -> float {
        const float px = (float)w + u;
        const float py = (float)h + v;
        const float fx0 = floorf(px);
        const float fy0 = floorf(py);
        const float wx1 = px - fx0, wx0 = 1.0f - wx1;
        const float wy1 = py - fy0, wy0 = 1.0f - wy1;
        const int ix0 = (int)fx0, iy0 = (int)fy0;
        const int ix1 = ix0 + 1, iy1 = iy0 + 1;
        const float bx0 = ((unsigned)ix0 < (unsigned)W) ? 1.0f : 0.0f;
        const float bx1 = ((unsigned)ix1 < (unsigned)W) ? 1.0f : 0.0f;
        const float by0 = ((unsigned)iy0 < (unsigned)H) ? 1.0f : 0.0f;
        const float by1 = ((unsigned)iy1 < (unsigned)H) ? 1.0f : 0.0f;
        // zeros-padding: OOB corner weights are 0 (same arithmetic as ref)
        float w00 = wx0 * wy0 * (bx0 * by0);
        float w10 = wx1 * wy0 * (bx1 * by0);
        float w01 = wx0 * wy1 * (bx0 * by1);
        float w11 = wx1 * wy1 * (bx1 * by1);
        const float m = w00 + w10 + w01 + w11;      // grid_sample(ones)
        const float mbit = (m < MASK_THRESH) ? 0.0f : 1.0f;
        w00 *= mbit; w10 *= mbit; w01 *= mbit; w11 *= mbit;
        const int x0c = min(max(ix0, 0), W - 1);
        const int x1c = min(max(ix1, 0), W - 1);
        const int y0c = min(max(iy0, 0), H - 1);
        const int y1c = min(max(iy1, 0), H - 1);

        float vr, vg, vb_;
        const bool inwin = (x0c >= base_c) & (x1c < base_c + WINC) &
                           (y0c >= base_r) & (y1c < base_r + WINR);
        if (inwin) {
            const int lx0 = x0c - base_c, lx1 = x1c - base_c;
            const int ly0 = y0c - base_r, ly1 = y1c - base_r;
            const int c00 = (int)win[ly0][lx0];
            const int c10 = (int)win[ly0][lx1];
            const int c01 = (int)win[ly1][lx0];
            const int c11 = (int)win[ly1][lx1];
            const floatx2 rg00 = __builtin_amdgcn_cvt_pk_f32_fp8(c00, false);
            const floatx2 rg10 = __builtin_amdgcn_cvt_pk_f32_fp8(c10, false);
            const floatx2 rg01 = __builtin_amdgcn_cvt_pk_f32_fp8(c01, false);
            const floatx2 rg11 = __builtin_amdgcn_cvt_pk_f32_fp8(c11, false);
            const float b00 = __builtin_amdgcn_cvt_f32_fp8(c00, 2);
            const float b10 = __builtin_amdgcn_cvt_f32_fp8(c10, 2);
            const float b01 = __builtin_amdgcn_cvt_f32_fp8(c01, 2);
            const float b11 = __builtin_amdgcn_cvt_f32_fp8(c11, 2);
            vr  = w00 * rg00.x + w10 * rg10.x + w01 * rg01.x + w11 * rg11.x;
            vg  = w00 * rg00.y + w10 * rg10.y + w01 * rg01.y + w11 * rg11.y;
            vb_ = w00 * b00   + w10 * b10   + w01 * b01   + w11 * b11;
        } else {
            const int o00 = y0c * W + x0c;
            const int o10 = y0c * W + x1c;
            const int o01 = y1c * W + x0c;
            const int o11 = y1c * W + x1c;
            const float* __restrict__ p0 = i1b;
            const float* __restrict__ p1 = i1b + HW;
            const float* __restrict__ p2 = i1b + 2 * HW;
            vr  = w00 * p0[o00] + w10 * p0[o10] + w01 * p0[o01] + w11 * p0[o11];
            vg  = w00 * p1[o00] + w10 * p1[o10] + w01 * p1[o01] + w11 * p1[o11];
            vb_ = w00 * p2[o00] + w10 * p2[o10] + w01 * p2[o01] + w11 * p2[o11];
        }
        const float dr = vr  - r2;
        const float dg = vg  - g2;
        const float db = vb_ - b2;
        // v_sqrt_f32 direct (~1 ulp) instead of sqrtf's ~8-instr fixup chain
        return __builtin_amdgcn_sqrtf(fmaf(dr, dr, EPS2))
             + __builtin_amdgcn_sqrtf(fmaf(dg, dg, EPS2))
             + __builtin_amdgcn_sqrtf(fmaf(db, db, EPS2));
    };

    // unroll 2 is load-bearing: full unroll inlines 16 px_charb bodies and
    // hoists 40 streaming dwords -> ~28 dwords/thread spilled to scratch
    // (rounds 8-10: WRITE_SIZE 64.59 MB of scratch round-trips, constant
    // across staging-loop changes). Two iterations = 4 px, 20 dwords in
    // flight: fits the compiler's 64-VGPR occupancy target.
    float acc = 0.0f;
#pragma unroll 2
    for (int it = 0; it < NIT; ++it) {
        const int h = h0 + 8 * it + 2 * wrow + rgrp;
        const int off = h * W + colbase;
        const float2 uu = *(const float2*)(uvb + off);
        const float2 vv = *(const float2*)(uvb + HW + off);
        const float2 r2 = *(const float2*)(i2b + off);
        const float2 g2 = *(const float2*)(i2b + HW + off);
        const float2 b2 = *(const float2*)(i2b + 2 * HW + off);
        acc += px_charb(colbase,     h, uu.x, vv.x, r2.x, g2.x, b2.x);
        acc += px_charb(colbase + 1, h, uu.y, vv.y, r2.y, g2.y, b2.y);
    }

    // block reduction: 4 waves of 64
#pragma unroll
    for (int offr = 32; offr > 0; offr >>= 1)
        acc += __shfl_down(acc, offr, 64);
    __shared__ float smem[4];
    if ((t & 63) == 0) smem[t >> 6] = acc;
    __syncthreads();
    if (t == 0)
        partial[blockIdx.x] = (smem[0] + smem[1]) + (smem[2] + smem[3]);
}

// Reduce 2304 partials -> scalar mean. Single block, float4 loads.
__global__ __launch_bounds__(256) void reduce_partial_kernel(
    const float* __restrict__ partial, float* __restrict__ out)
{
    float acc = 0.0f;
    const float4* __restrict__ p4 = (const float4*)partial;  // 576 float4
    for (int i = threadIdx.x; i < NTILES / 4; i += 256) {
        const float4 v = p4[i];
        acc += (v.x + v.y) + (v.z + v.w);
    }
#pragma unroll
    for (int off = 32; off > 0; off >>= 1)
        acc += __shfl_down(acc, off, 64);
    __shared__ float smem[4];
    if ((threadIdx.x & 63) == 0) smem[threadIdx.x >> 6] = acc;
    __syncthreads();
    if (threadIdx.x == 0) {
        const float s = (smem[0] + smem[1]) + (smem[2] + smem[3]);
        out[0] = s * (1.0f / (float)((long long)B * C * H * W));
    }
}

extern "C" void kernel_launch(void* const* d_in, const int* in_sizes, int n_in,
                              void* d_out, int out_size, void* d_ws, size_t ws_size,
                              hipStream_t stream) {
    const float* img1 = (const float*)d_in[0];
    const float* img2 = (const float*)d_in[1];
    const float* uv   = (const float*)d_in[2];
    float* out = (float*)d_out;
    float* partial = (float*)d_ws;   // NTILES floats = 9.2 KiB

    warp_charb_fp8_kernel<<<NTILES, 256, 0, stream>>>(img1, img2, uv, partial);
    reduce_partial_kernel<<<1, 256, 0, stream>>>(partial, out);
}

// Round 12
// 65.540 us; speedup vs baseline: 1.4870x; 1.0288x over previous
//
#include <hip/hip_runtime.h>

typedef float floatx2 __attribute__((ext_vector_type(2)));

// Problem constants (fixed by setup_inputs): B=16, C=3, H=W=768.
constexpr int B = 16, C = 3, H = 768, W = 768;
constexpr int HW = H * W;
constexpr float EPS2 = 1e-6f;         // 0.001^2
constexpr float MASK_THRESH = 0.9999f;
constexpr int NXCD = 8;

// Tiling: 64x64 px per block, margin 16 covers |flow|<=16 (4 sigma of N(0,16)).
// Window overfetch (96x96)/(64x64) = 2.25x (was 3x at 32x64 tiles).
constexpr int TH = 64, TW = 64, M = 16;
constexpr int WINR = TH + 2 * M;      // 96
constexpr int WINC = TW + 2 * M;      // 96 payload columns
constexpr int WSTRIDE = 101;          // row stride in words; 101%32=5, coprime
constexpr int TILES_H = H / TH;       // 12
constexpr int TILES_W = W / TW;       // 12
constexpr int NTILES = B * TILES_H * TILES_W;  // 2304
constexpr int NIT = 8;                // 8 iterations x 2 px/thread = 16 px

__global__ __launch_bounds__(256, 4) void warp_charb_fp8_kernel(
    const float* __restrict__ img1,
    const float* __restrict__ img2,
    const float* __restrict__ uv,
    float* __restrict__ partial)
{
    // XCD-chunked swizzle: contiguous band of tiles per XCD (2304 % 8 == 0).
    const int bid = blockIdx.x;
    const int tile = (bid % NXCD) * (NTILES / NXCD) + bid / NXCD;
    const int b  = tile / (TILES_H * TILES_W);
    const int tr = tile - b * (TILES_H * TILES_W);
    const int th = tr / TILES_W;
    const int tw = tr - th * TILES_W;
    const int h0 = th * TH;
    const int w0 = tw * TW;
    const int base_r = h0 - M;
    const int base_c = w0 - M;
    const int t = threadIdx.x;
    const int lane = t & 63;
    const int wrow = t >> 6;               // 0..3
    const int rgrp = lane >> 5;            // 0/1: which row of the pair
    const int cp   = lane & 31;            // col-pair index
    const int colbase = w0 + 2 * cp;

    // Packed RGBA-fp8 window: one u32 per pixel holds all 3 channels.
    // 96*101*4 = 38784 B -> 4 blocks/CU LDS cap.
    __shared__ unsigned win[WINR][WSTRIDE];

    const float* __restrict__ i1b = img1 + b * (C * HW);
    const float* __restrict__ uvb = uv + b * (2 * HW);
    const float* __restrict__ i2b = img2 + b * (C * HW);

    // ---- Stage gather window (coalesced float4 x3 -> packed fp8) ----------
    // base_c and gc are multiples of 4, W%4==0 => every 4-chunk is either
    // fully in-bounds or fully OOB; no partial case.
    constexpr int CH4 = WINC / 4;             // 24
#pragma unroll 1
    for (int s = 0; s < (WINR * CH4) / 256; ++s) {   // 9 passes
        const int idx = t + s * 256;
        const int wy = idx / CH4;
        const int j4 = idx - wy * CH4;
        const int gr = base_r + wy;
        const int gc = base_c + 4 * j4;
        unsigned pk0 = 0u, pk1 = 0u, pk2 = 0u, pk3 = 0u;
        if ((unsigned)gr < (unsigned)H && (unsigned)gc <= (unsigned)(W - 4)) {
            const float* __restrict__ rp = i1b + gr * W + gc;
            const float4 r4 = *(const float4*)(rp);
            const float4 g4 = *(const float4*)(rp + HW);
            const float4 b4 = *(const float4*)(rp + 2 * HW);
            int v;
            v = __builtin_amdgcn_cvt_pk_fp8_f32(r4.x, g4.x, 0, false);
            pk0 = (unsigned)__builtin_amdgcn_cvt_pk_fp8_f32(b4.x, 0.0f, v, true);
            v = __builtin_amdgcn_cvt_pk_fp8_f32(r4.y, g4.y, 0, false);
            pk1 = (unsigned)__builtin_amdgcn_cvt_pk_fp8_f32(b4.y, 0.0f, v, true);
            v = __builtin_amdgcn_cvt_pk_fp8_f32(r4.z, g4.z, 0, false);
            pk2 = (unsigned)__builtin_amdgcn_cvt_pk_fp8_f32(b4.z, 0.0f, v, true);
            v = __builtin_amdgcn_cvt_pk_fp8_f32(r4.w, g4.w, 0, false);
            pk3 = (unsigned)__builtin_amdgcn_cvt_pk_fp8_f32(b4.w, 0.0f, v, true);
        }
        unsigned* __restrict__ dst = &win[wy][4 * j4];
        dst[0] = pk0; dst[1] = pk1; dst[2] = pk2; dst[3] = pk3;
    }

    // ---- Prologue: iteration-0 streaming loads issued BEFORE the barrier
    // so their latency hides under the staging drain -------------------------
    const int off0 = (h0 + 2 * wrow + rgrp) * W + colbase;
    float2 uu = *(const float2*)(uvb + off0);
    float2 vv = *(const float2*)(uvb + HW + off0);
    float2 r2 = *(const float2*)(i2b + off0);
    float2 g2 = *(const float2*)(i2b + HW + off0);
    float2 b2 = *(const float2*)(i2b + 2 * HW + off0);
    __syncthreads();

    // ---- Warp + Charbonnier: 8 iters x 2 independent pixels ---------------
    auto px_charb = [&](int w, int h, float u, float v,
                        float r2_, float g2_, float b2_) -> float {
        const float px = (float)w + u;
        const float py = (float)h + v;
        const float fx0 = floorf(px);
        const float fy0 = floorf(py);
        const float wx1 = px - fx0, wx0 = 1.0f - wx1;
        const float wy1 = py - fy0, wy0 = 1.0f - wy1;
        const int ix0 = (int)fx0, iy0 = (int)fy0;
        const int ix1 = ix0 + 1, iy1 = iy0 + 1;
        const float bx0 = ((unsigned)ix0 < (unsigned)W) ? 1.0f : 0.0f;
        const float bx1 = ((unsigned)ix1 < (unsigned)W) ? 1.0f : 0.0f;
        const float by0 = ((unsigned)iy0 < (unsigned)H) ? 1.0f : 0.0f;
        const float by1 = ((unsigned)iy1 < (unsigned)H) ? 1.0f : 0.0f;
        // zeros-padding: OOB corner weights are 0 (same arithmetic as ref)
        float w00 = wx0 * wy0 * (bx0 * by0);
        float w10 = wx1 * wy0 * (bx1 * by0);
        float w01 = wx0 * wy1 * (bx0 * by1);
        float w11 = wx1 * wy1 * (bx1 * by1);
        const float m = w00 + w10 + w01 + w11;      // grid_sample(ones)
        const float mbit = (m < MASK_THRESH) ? 0.0f : 1.0f;
        w00 *= mbit; w10 *= mbit; w01 *= mbit; w11 *= mbit;
        const int x0c = min(max(ix0, 0), W - 1);
        const int x1c = min(max(ix1, 0), W - 1);
        const int y0c = min(max(iy0, 0), H - 1);
        const int y1c = min(max(iy1, 0), H - 1);

        float vr, vg, vb_;
        const bool inwin = (x0c >= base_c) & (x1c < base_c + WINC) &
                           (y0c >= base_r) & (y1c < base_r + WINR);
        if (inwin) {
            const int lx0 = x0c - base_c, lx1 = x1c - base_c;
            const int ly0 = y0c - base_r, ly1 = y1c - base_r;
            const int c00 = (int)win[ly0][lx0];
            const int c10 = (int)win[ly0][lx1];
            const int c01 = (int)win[ly1][lx0];
            const int c11 = (int)win[ly1][lx1];
            const floatx2 rg00 = __builtin_amdgcn_cvt_pk_f32_fp8(c00, false);
            const floatx2 rg10 = __builtin_amdgcn_cvt_pk_f32_fp8(c10, false);
            const floatx2 rg01 = __builtin_amdgcn_cvt_pk_f32_fp8(c01, false);
            const floatx2 rg11 = __builtin_amdgcn_cvt_pk_f32_fp8(c11, false);
            const float b00 = __builtin_amdgcn_cvt_f32_fp8(c00, 2);
            const float b10 = __builtin_amdgcn_cvt_f32_fp8(c10, 2);
            const float b01 = __builtin_amdgcn_cvt_f32_fp8(c01, 2);
            const float b11 = __builtin_amdgcn_cvt_f32_fp8(c11, 2);
            vr  = w00 * rg00.x + w10 * rg10.x + w01 * rg01.x + w11 * rg11.x;
            vg  = w00 * rg00.y + w10 * rg10.y + w01 * rg01.y + w11 * rg11.y;
            vb_ = w00 * b00   + w10 * b10   + w01 * b01   + w11 * b11;
        } else {
            const int o00 = y0c * W + x0c;
            const int o10 = y0c * W + x1c;
            const int o01 = y1c * W + x0c;
            const int o11 = y1c * W + x1c;
            const float* __restrict__ p0 = i1b;
            const float* __restrict__ p1 = i1b + HW;
            const float* __restrict__ p2 = i1b + 2 * HW;
            vr  = w00 * p0[o00] + w10 * p0[o10] + w01 * p0[o01] + w11 * p0[o11];
            vg  = w00 * p1[o00] + w10 * p1[o10] + w01 * p1[o01] + w11 * p1[o11];
            vb_ = w00 * p2[o00] + w10 * p2[o10] + w01 * p2[o01] + w11 * p2[o11];
        }
        const float dr = vr  - r2_;
        const float dg = vg  - g2_;
        const float db = vb_ - b2_;
        // v_sqrt_f32 direct (~1 ulp) instead of sqrtf's ~8-instr fixup chain
        return __builtin_amdgcn_sqrtf(fmaf(dr, dr, EPS2))
             + __builtin_amdgcn_sqrtf(fmaf(dg, dg, EPS2))
             + __builtin_amdgcn_sqrtf(fmaf(db, db, EPS2));
    };

    // 1-deep software pipeline, unroll 1 (load-bearing: full unroll hoists
    // all streaming loads -> scratch spill, rounds 8-10 WRITE_SIZE 64.6 MB;
    // unroll 2 without prefetch leaves each iteration's L2/L3 round-trip
    // naked in the dependency chain). Next-iteration loads issue first,
    // current iteration computes under them.
    float acc = 0.0f;
#pragma unroll 1
    for (int it = 0; it < NIT; ++it) {
        const int itn = min(it + 1, NIT - 1);
        const int offn = (h0 + 8 * itn + 2 * wrow + rgrp) * W + colbase;
        const float2 uun = *(const float2*)(uvb + offn);
        const float2 vvn = *(const float2*)(uvb + HW + offn);
        const float2 r2n = *(const float2*)(i2b + offn);
        const float2 g2n = *(const float2*)(i2b + HW + offn);
        const float2 b2n = *(const float2*)(i2b + 2 * HW + offn);

        const int h = h0 + 8 * it + 2 * wrow + rgrp;
        acc += px_charb(colbase,     h, uu.x, vv.x, r2.x, g2.x, b2.x);
        acc += px_charb(colbase + 1, h, uu.y, vv.y, r2.y, g2.y, b2.y);

        uu = uun; vv = vvn; r2 = r2n; g2 = g2n; b2 = b2n;
    }

    // block reduction: 4 waves of 64
#pragma unroll
    for (int offr = 32; offr > 0; offr >>= 1)
        acc += __shfl_down(acc, offr, 64);
    __shared__ float smem[4];
    if ((t & 63) == 0) smem[t >> 6] = acc;
    __syncthreads();
    if (t == 0)
        partial[blockIdx.x] = (smem[0] + smem[1]) + (smem[2] + smem[3]);
}

// Reduce 2304 partials -> scalar mean. Single block, float4 loads.
__global__ __launch_bounds__(256) void reduce_partial_kernel(
    const float* __restrict__ partial, float* __restrict__ out)
{
    float acc = 0.0f;
    const float4* __restrict__ p4 = (const float4*)partial;  // 576 float4
    for (int i = threadIdx.x; i < NTILES / 4; i += 256) {
        const float4 v = p4[i];
        acc += (v.x + v.y) + (v.z + v.w);
    }
#pragma unroll
    for (int off = 32; off > 0; off >>= 1)
        acc += __shfl_down(acc, off, 64);
    __shared__ float smem[4];
    if ((threadIdx.x & 63) == 0) smem[threadIdx.x >> 6] = acc;
    __syncthreads();
    if (threadIdx.x == 0) {
        const float s = (smem[0] + smem[1]) + (smem[2] + smem[3]);
        out[0] = s * (1.0f / (float)((long long)B * C * H * W));
    }
}

extern "C" void kernel_launch(void* const* d_in, const int* in_sizes, int n_in,
                              void* d_out, int out_size, void* d_ws, size_t ws_size,
                              hipStream_t stream) {
    const float* img1 = (const float*)d_in[0];
    const float* img2 = (const float*)d_in[1];
    const float* uv   = (const float*)d_in[2];
    float* out = (float*)d_out;
    float* partial = (float*)d_ws;   // NTILES floats = 9.2 KiB

    warp_charb_fp8_kernel<<<NTILES, 256, 0, stream>>>(img1, img2, uv, partial);
    reduce_partial_kernel<<<1, 256, 0, stream>>>(partial, out);
}

// Round 13
// 64.461 us; speedup vs baseline: 1.5119x; 1.0167x over previous
//
#include <hip/hip_runtime.h>

typedef float floatx2 __attribute__((ext_vector_type(2)));

// Problem constants (fixed by setup_inputs): B=16, C=3, H=W=768.
constexpr int B = 16, C = 3, H = 768, W = 768;
constexpr int HW = H * W;
constexpr float EPS2 = 1e-6f;         // 0.001^2
constexpr float MASK_THRESH = 0.9999f;
constexpr int NXCD = 8;

// Tiling: 48x64 px per block, margin 16 covers |flow|<=16 (4 sigma of N(0,16)).
// Window 80x96 fp8-packed = 31.0 KB LDS -> 5 blocks/CU (was 4 at 64x64).
// Halo overfetch (80x96)/(48x64) = 2.5x (vs 2.25x) -- traded for +25% waves.
constexpr int TH = 48, TW = 64, M = 16;
constexpr int WINR = TH + 2 * M;      // 80
constexpr int WINC = TW + 2 * M;      // 96 payload columns
constexpr int WSTRIDE = 97;           // row stride in words; 97%32=1, coprime
constexpr int TILES_H = H / TH;       // 16
constexpr int TILES_W = W / TW;       // 12
constexpr int NTILES = B * TILES_H * TILES_W;  // 3072
constexpr int NIT = 6;                // 6 iterations x 2 px/thread = 12 px

__global__ __launch_bounds__(256, 4) void warp_charb_fp8_kernel(
    const float* __restrict__ img1,
    const float* __restrict__ img2,
    const float* __restrict__ uv,
    float* __restrict__ partial)
{
    // XCD-chunked swizzle: contiguous band of tiles per XCD (3072 % 8 == 0).
    const int bid = blockIdx.x;
    const int tile = (bid % NXCD) * (NTILES / NXCD) + bid / NXCD;
    const int b  = tile / (TILES_H * TILES_W);
    const int tr = tile - b * (TILES_H * TILES_W);
    const int th = tr / TILES_W;
    const int tw = tr - th * TILES_W;
    const int h0 = th * TH;
    const int w0 = tw * TW;
    const int base_r = h0 - M;
    const int base_c = w0 - M;
    const int t = threadIdx.x;
    const int lane = t & 63;
    const int wrow = t >> 6;               // 0..3
    const int rgrp = lane >> 5;            // 0/1: which row of the pair
    const int cp   = lane & 31;            // col-pair index
    const int colbase = w0 + 2 * cp;

    // Packed RGBA-fp8 window: one u32 per pixel holds all 3 channels.
    // 80*97*4 = 31040 B -> 5 blocks/CU LDS cap (20 waves/CU).
    __shared__ unsigned win[WINR][WSTRIDE];

    const float* __restrict__ i1b = img1 + b * (C * HW);
    const float* __restrict__ uvb = uv + b * (2 * HW);
    const float* __restrict__ i2b = img2 + b * (C * HW);

    // ---- Stage gather window (coalesced float4 x3 -> packed fp8) ----------
    // base_c and gc are multiples of 4, W%4==0 => every 4-chunk is either
    // fully in-bounds or fully OOB; no partial case.
    // unroll 1 + bounded live range: full unroll of staging/compute loops
    // hoists all loads -> scratch spill (rounds 8-10: 64.6 MB WRITE_SIZE).
    constexpr int CH4 = WINC / 4;             // 24
    constexpr int CHUNKS = WINR * CH4;        // 1920 (7.5 passes of 256)
#pragma unroll 1
    for (int idx = t; idx < CHUNKS; idx += 256) {
        const int wy = idx / CH4;
        const int j4 = idx - wy * CH4;
        const int gr = base_r + wy;
        const int gc = base_c + 4 * j4;
        unsigned pk0 = 0u, pk1 = 0u, pk2 = 0u, pk3 = 0u;
        if ((unsigned)gr < (unsigned)H && (unsigned)gc <= (unsigned)(W - 4)) {
            const float* __restrict__ rp = i1b + gr * W + gc;
            const float4 r4 = *(const float4*)(rp);
            const float4 g4 = *(const float4*)(rp + HW);
            const float4 b4 = *(const float4*)(rp + 2 * HW);
            int v;
            v = __builtin_amdgcn_cvt_pk_fp8_f32(r4.x, g4.x, 0, false);
            pk0 = (unsigned)__builtin_amdgcn_cvt_pk_fp8_f32(b4.x, 0.0f, v, true);
            v = __builtin_amdgcn_cvt_pk_fp8_f32(r4.y, g4.y, 0, false);
            pk1 = (unsigned)__builtin_amdgcn_cvt_pk_fp8_f32(b4.y, 0.0f, v, true);
            v = __builtin_amdgcn_cvt_pk_fp8_f32(r4.z, g4.z, 0, false);
            pk2 = (unsigned)__builtin_amdgcn_cvt_pk_fp8_f32(b4.z, 0.0f, v, true);
            v = __builtin_amdgcn_cvt_pk_fp8_f32(r4.w, g4.w, 0, false);
            pk3 = (unsigned)__builtin_amdgcn_cvt_pk_fp8_f32(b4.w, 0.0f, v, true);
        }
        unsigned* __restrict__ dst = &win[wy][4 * j4];
        dst[0] = pk0; dst[1] = pk1; dst[2] = pk2; dst[3] = pk3;
    }

    // ---- Prologue: iteration-0 streaming loads issued BEFORE the barrier
    // so their latency hides under the staging drain -------------------------
    const int off0 = (h0 + 2 * wrow + rgrp) * W + colbase;
    float2 uu = *(const float2*)(uvb + off0);
    float2 vv = *(const float2*)(uvb + HW + off0);
    float2 r2 = *(const float2*)(i2b + off0);
    float2 g2 = *(const float2*)(i2b + HW + off0);
    float2 b2 = *(const float2*)(i2b + 2 * HW + off0);
    __syncthreads();

    // ---- Warp + Charbonnier: 6 iters x 2 independent pixels ---------------
    auto px_charb = [&](int w, int h, float u, float v,
                        float r2_, float g2_, float b2_) -> float {
        const float px = (float)w + u;
        const float py = (float)h + v;
        const float fx0 = floorf(px);
        const float fy0 = floorf(py);
        const float wx1 = px - fx0, wx0 = 1.0f - wx1;
        const float wy1 = py - fy0, wy0 = 1.0f - wy1;
        const int ix0 = (int)fx0, iy0 = (int)fy0;
        const int ix1 = ix0 + 1, iy1 = iy0 + 1;
        const float bx0 = ((unsigned)ix0 < (unsigned)W) ? 1.0f : 0.0f;
        const float bx1 = ((unsigned)ix1 < (unsigned)W) ? 1.0f : 0.0f;
        const float by0 = ((unsigned)iy0 < (unsigned)H) ? 1.0f : 0.0f;
        const float by1 = ((unsigned)iy1 < (unsigned)H) ? 1.0f : 0.0f;
        // zeros-padding: OOB corner weights are 0 (same arithmetic as ref)
        float w00 = wx0 * wy0 * (bx0 * by0);
        float w10 = wx1 * wy0 * (bx1 * by0);
        float w01 = wx0 * wy1 * (bx0 * by1);
        float w11 = wx1 * wy1 * (bx1 * by1);
        const float m = w00 + w10 + w01 + w11;      // grid_sample(ones)
        const float mbit = (m < MASK_THRESH) ? 0.0f : 1.0f;
        w00 *= mbit; w10 *= mbit; w01 *= mbit; w11 *= mbit;
        const int x0c = min(max(ix0, 0), W - 1);
        const int x1c = min(max(ix1, 0), W - 1);
        const int y0c = min(max(iy0, 0), H - 1);
        const int y1c = min(max(iy1, 0), H - 1);

        float vr, vg, vb_;
        const bool inwin = (x0c >= base_c) & (x1c < base_c + WINC) &
                           (y0c >= base_r) & (y1c < base_r + WINR);
        if (inwin) {
            const int lx0 = x0c - base_c, lx1 = x1c - base_c;
            const int ly0 = y0c - base_r, ly1 = y1c - base_r;
            const int c00 = (int)win[ly0][lx0];
            const int c10 = (int)win[ly0][lx1];
            const int c01 = (int)win[ly1][lx0];
            const int c11 = (int)win[ly1][lx1];
            const floatx2 rg00 = __builtin_amdgcn_cvt_pk_f32_fp8(c00, false);
            const floatx2 rg10 = __builtin_amdgcn_cvt_pk_f32_fp8(c10, false);
            const floatx2 rg01 = __builtin_amdgcn_cvt_pk_f32_fp8(c01, false);
            const floatx2 rg11 = __builtin_amdgcn_cvt_pk_f32_fp8(c11, false);
            const float b00 = __builtin_amdgcn_cvt_f32_fp8(c00, 2);
            const float b10 = __builtin_amdgcn_cvt_f32_fp8(c10, 2);
            const float b01 = __builtin_amdgcn_cvt_f32_fp8(c01, 2);
            const float b11 = __builtin_amdgcn_cvt_f32_fp8(c11, 2);
            vr  = w00 * rg00.x + w10 * rg10.x + w01 * rg01.x + w11 * rg11.x;
            vg  = w00 * rg00.y + w10 * rg10.y + w01 * rg01.y + w11 * rg11.y;
            vb_ = w00 * b00   + w10 * b10   + w01 * b01   + w11 * b11;
        } else {
            const int o00 = y0c * W + x0c;
            const int o10 = y0c * W + x1c;
            const int o01 = y1c * W + x0c;
            const int o11 = y1c * W + x1c;
            const float* __restrict__ p0 = i1b;
            const float* __restrict__ p1 = i1b + HW;
            const float* __restrict__ p2 = i1b + 2 * HW;
            vr  = w00 * p0[o00] + w10 * p0[o10] + w01 * p0[o01] + w11 * p0[o11];
            vg  = w00 * p1[o00] + w10 * p1[o10] + w01 * p1[o01] + w11 * p1[o11];
            vb_ = w00 * p2[o00] + w10 * p2[o10] + w01 * p2[o01] + w11 * p2[o11];
        }
        const float dr = vr  - r2_;
        const float dg = vg  - g2_;
        const float db = vb_ - b2_;
        // v_sqrt_f32 direct (~1 ulp) instead of sqrtf's ~8-instr fixup chain
        return __builtin_amdgcn_sqrtf(fmaf(dr, dr, EPS2))
             + __builtin_amdgcn_sqrtf(fmaf(dg, dg, EPS2))
             + __builtin_amdgcn_sqrtf(fmaf(db, db, EPS2));
    };

    // 1-deep software pipeline, unroll 1 (load-bearing: full unroll hoists
    // all streaming loads -> scratch spill; see rounds 8-11 ledger).
    // Next-iteration loads issue first, current iteration computes under them.
    float acc = 0.0f;
#pragma unroll 1
    for (int it = 0; it < NIT; ++it) {
        const int itn = min(it + 1, NIT - 1);
        const int offn = (h0 + 8 * itn + 2 * wrow + rgrp) * W + colbase;
        const float2 uun = *(const float2*)(uvb + offn);
        const float2 vvn = *(const float2*)(uvb + HW + offn);
        const float2 r2n = *(const float2*)(i2b + offn);
        const float2 g2n = *(const float2*)(i2b + HW + offn);
        const float2 b2n = *(const float2*)(i2b + 2 * HW + offn);

        const int h = h0 + 8 * it + 2 * wrow + rgrp;
        acc += px_charb(colbase,     h, uu.x, vv.x, r2.x, g2.x, b2.x);
        acc += px_charb(colbase + 1, h, uu.y, vv.y, r2.y, g2.y, b2.y);

        uu = uun; vv = vvn; r2 = r2n; g2 = g2n; b2 = b2n;
    }

    // block reduction: 4 waves of 64
#pragma unroll
    for (int offr = 32; offr > 0; offr >>= 1)
        acc += __shfl_down(acc, offr, 64);
    __shared__ float smem[4];
    if ((t & 63) == 0) smem[t >> 6] = acc;
    __syncthreads();
    if (t == 0)
        partial[blockIdx.x] = (smem[0] + smem[1]) + (smem[2] + smem[3]);
}

// Reduce 3072 partials -> scalar mean. Single block, float4 loads.
__global__ __launch_bounds__(256) void reduce_partial_kernel(
    const float* __restrict__ partial, float* __restrict__ out)
{
    float acc = 0.0f;
    const float4* __restrict__ p4 = (const float4*)partial;  // 768 float4
    for (int i = threadIdx.x; i < NTILES / 4; i += 256) {
        const float4 v = p4[i];
        acc += (v.x + v.y) + (v.z + v.w);
    }
#pragma unroll
    for (int off = 32; off > 0; off >>= 1)
        acc += __shfl_down(acc, off, 64);
    __shared__ float smem[4];
    if ((threadIdx.x & 63) == 0) smem[threadIdx.x >> 6] = acc;
    __syncthreads();
    if (threadIdx.x == 0) {
        const float s = (smem[0] + smem[1]) + (smem[2] + smem[3]);
        out[0] = s * (1.0f / (float)((long long)B * C * H * W));
    }
}

extern "C" void kernel_launch(void* const* d_in, const int* in_sizes, int n_in,
                              void* d_out, int out_size, void* d_ws, size_t ws_size,
                              hipStream_t stream) {
    const float* img1 = (const float*)d_in[0];
    const float* img2 = (const float*)d_in[1];
    const float* uv   = (const float*)d_in[2];
    float* out = (float*)d_out;
    float* partial = (float*)d_ws;   // NTILES floats = 12 KiB

    warp_charb_fp8_kernel<<<NTILES, 256, 0, stream>>>(img1, img2, uv, partial);
    reduce_partial_kernel<<<1, 256, 0, stream>>>(partial, out);
}